// Round 6
// baseline (94.735 us; speedup 1.0000x reference)
//
#include <hip/hip_runtime.h>
#include <hip/hip_cooperative_groups.h>
#include <stdint.h>

namespace cg = cooperative_groups;

#define S 2048
#define B 256
#define THRESH 4

typedef unsigned long long u64;
typedef uint32_t u32;

// ws layout:
//  [0,      65536)   ptok : S*4 u64  (64 KB)  bit-packed token rows
//  [65536,  98304)   kc   : S*8 u16  (32 KB)
//  [98304, 131072)   pc   : S*8 u16  (32 KB)
//  [131072,135168)   ptab : 512 u64  ( 4 KB)  bit-packed tables

// 8 table lookups for one packed address pair (a0: heads 0-3, a1: heads 4-7)
__device__ __forceinline__ int vote8(const u32* s_tab, u64 a0, u64 a1) {
    int v = 0;
    #pragma unroll
    for (int h = 0; h < 4; ++h) {
        { u32 w = (u32)(a0 >> (16 * h + 5)) & 127;
          v += (int)((s_tab[h * 128 + w] >> ((u32)(a0 >> (16 * h)) & 31)) & 1); }
        { u32 w = (u32)(a1 >> (16 * h + 5)) & 127;
          v += (int)((s_tab[(h + 4) * 128 + w] >> ((u32)(a1 >> (16 * h)) & 31)) & 1); }
    }
    return v;
}

__launch_bounds__(256)
__global__ void fused_kernel(const int* __restrict__ tokens,
                             const int* __restrict__ conn,
                             const int* __restrict__ table,
                             u64* __restrict__ ptok,
                             uint16_t* __restrict__ kc,
                             uint16_t* __restrict__ pc,
                             u64* __restrict__ ptab,
                             int* __restrict__ out) {
    __shared__ u32 s_tab[1024];                 // 4 KB packed tables
    __shared__ u64 s_part[8][256];              // 16 KB xor-reduction staging
    __shared__ u64 s_p2[8][32];
    __shared__ u64 s_fin[8];
    __shared__ u64 s_kred[4];
    __shared__ u64 s_row[2][4];
    __shared__ __align__(16) uint16_t s_qc[2][8];

    const int b   = blockIdx.x;                 // 0..1023
    const int tid = threadIdx.x;
    const int lane = tid & 63, wave = tid >> 6;

    // rows: pair (2046-b, b) sums to exactly 2048 pairs; block 1023 takes {2047,1023}
    const int rowA = (b == 1023) ? 2047 : 2046 - b;
    const int rowB = (b == 1023) ? 1023 : b;

    // ================= phase 1: prep own rows =================
    {
        const int tA = tokens[rowA * B + tid];
        const int tB = tokens[rowB * B + tid];
        const u64 mA = __ballot(tA != 0);
        const u64 mB = __ballot(tB != 0);
        if (lane == 0) {
            s_row[0][wave] = mA; ptok[rowA * 4 + wave] = mA;
            s_row[1][wave] = mB; ptok[rowB * 4 + wave] = mB;
        }
        __syncthreads();
        if (tid < 16) {
            const int ri = tid >> 3, h = tid & 7;
            const int r = ri ? rowB : rowA;
            int q = 0, k = 0, p = 0;
            #pragma unroll
            for (int n = 0; n < 12; ++n) {
                const int c = conn[h * 12 + n];
                if (c < B) {
                    q |= (int)((s_row[ri][c >> 6] >> (c & 63)) & 1) << n;
                } else if (c < 2 * B) {
                    const int cc = c - B;
                    k |= (int)((s_row[ri][cc >> 6] >> (cc & 63)) & 1) << n;
                } else {
                    p |= ((r >> (c - 2 * B)) & 1) << n;
                }
            }
            s_qc[ri][h] = (uint16_t)q;
            kc[r * 8 + h] = (uint16_t)k;
            pc[r * 8 + h] = (uint16_t)p;
        }
        if (b < 2) {                            // blocks 0,1 pack the table
            const int k = b * 256 + tid;        // 0..511
            const int h = k >> 6, w = k & 63;
            const int* src = table + h * 4096 + w * 64;
            u64 v = 0;
            #pragma unroll 8
            for (int x = 0; x < 64; ++x) v |= (u64)(src[x] & 1) << x;
            ptab[k] = v;
        }
    }

    cg::this_grid().sync();

    // ================= phase 2: main loop =================
    ((uint4*)s_tab)[tid] = ((const uint4*)ptab)[tid];
    __syncthreads();

    const u64 qA0 = ((const u64*)s_qc[0])[0], qA1 = ((const u64*)s_qc[0])[1];
    const u64 qB0 = ((const u64*)s_qc[1])[0], qB1 = ((const u64*)s_qc[1])[1];

    const int nA    = rowA + 1;
    const int total = nA + rowB + 1;            // 2048 (or 3072 for b==1023)
    const int niter = total >> 9;               // 4 (or 6)

    u64 ax0=0, ax1=0, ax2=0, ax3=0;             // rowA parity acc
    u64 bx0=0, bx1=0, bx2=0, bx3=0;             // rowB parity acc
    int bvA = -1, bjA = 0, bvB = -1, bjB = 0;

    for (int it = 0; it < niter; ++it) {
        #pragma unroll
        for (int s = 0; s < 2; ++s) {
            const int v = (it << 9) + (s << 8) + tid;   // every v < total is real work
            const bool isA = (v < nA);
            const int j = isA ? v : v - nA;
            const int d = (isA ? rowA : rowB) - j;

            const ulonglong2 kk = *(const ulonglong2*)(kc + j * 8);
            const ulonglong2 pp = *(const ulonglong2*)(pc + d * 8);
            const ulonglong2 t0 = *(const ulonglong2*)(ptok + j * 4);
            const ulonglong2 t1 = *(const ulonglong2*)(ptok + j * 4 + 2);

            const u64 a0 = (isA ? qA0 : qB0) + kk.x + pp.x;   // disjoint bits: no carry
            const u64 a1 = (isA ? qA1 : qB1) + kk.y + pp.y;
            const int vt = vote8(s_tab, a0, a1);

            const bool inc = (vt >= THRESH);
            const u64 mskA = (inc && isA)  ? ~0ull : 0ull;
            const u64 mskB = (inc && !isA) ? ~0ull : 0ull;
            ax0 ^= t0.x & mskA; ax1 ^= t0.y & mskA; ax2 ^= t1.x & mskA; ax3 ^= t1.y & mskA;
            bx0 ^= t0.x & mskB; bx1 ^= t0.y & mskB; bx2 ^= t1.x & mskB; bx3 ^= t1.y & mskB;

            const int cA = isA ? vt : -1;
            const int cB = isA ? -1 : vt;
            if (cA > bvA) { bvA = cA; bjA = j; }   // strict >: earliest j wins ties
            if (cB > bvB) { bvB = cB; bjB = j; }
        }
    }

    // ---- reduction: keys via small butterfly, xors via staged LDS tree ----
    u32 keyA = (u32)(((bvA + 1) << 16) | (2047 - bjA));
    u32 keyB = (u32)(((bvB + 1) << 16) | (2047 - bjB));
    #pragma unroll
    for (int off = 32; off; off >>= 1) {
        keyA = max(keyA, (u32)__shfl_xor((int)keyA, off));
        keyB = max(keyB, (u32)__shfl_xor((int)keyB, off));
    }

    s_part[0][tid] = ax0; s_part[1][tid] = ax1; s_part[2][tid] = ax2; s_part[3][tid] = ax3;
    s_part[4][tid] = bx0; s_part[5][tid] = bx1; s_part[6][tid] = bx2; s_part[7][tid] = bx3;
    if (lane == 0) s_kred[wave] = ((u64)keyA << 32) | keyB;
    __syncthreads();

    {   // stage 1: 8 words x 32 chunks, strided reads (2-way banks = free)
        const int w = tid >> 5, c = tid & 31;
        u64 x = s_part[w][c]       ^ s_part[w][c + 32]  ^ s_part[w][c + 64]  ^ s_part[w][c + 96]
              ^ s_part[w][c + 128] ^ s_part[w][c + 160] ^ s_part[w][c + 192] ^ s_part[w][c + 224];
        s_p2[w][c] = x;
    }
    __syncthreads();
    if (tid < 64) {                             // stage 2: fold 32 -> 1 per word
        const int w = tid >> 3, c = tid & 7;
        u64 x = s_p2[w][c] ^ s_p2[w][c + 8] ^ s_p2[w][c + 16] ^ s_p2[w][c + 24];
        x ^= __shfl_xor(x, 4); x ^= __shfl_xor(x, 2); x ^= __shfl_xor(x, 1);
        if (c == 0) s_fin[w] = x;
    }
    __syncthreads();

    const u32 fkA = max(max((u32)(s_kred[0] >> 32), (u32)(s_kred[1] >> 32)),
                        max((u32)(s_kred[2] >> 32), (u32)(s_kred[3] >> 32)));
    const u32 fkB = max(max((u32)s_kred[0], (u32)s_kred[1]),
                        max((u32)s_kred[2], (u32)s_kred[3]));

    const int widx = tid >> 6, bitb = tid & 63;
    int oA, oB;
    if ((fkA >> 16) > THRESH) {                 // bestv+1 > 4  <=>  bestv >= THRESH
        oA = (int)((s_fin[widx] >> bitb) & 1);
    } else {
        const int bj = 2047 - (int)(fkA & 0xFFFF);
        oA = (int)((ptok[bj * 4 + widx] >> bitb) & 1);
    }
    if ((fkB >> 16) > THRESH) {
        oB = (int)((s_fin[4 + widx] >> bitb) & 1);
    } else {
        const int bj = 2047 - (int)(fkB & 0xFFFF);
        oB = (int)((ptok[bj * 4 + widx] >> bitb) & 1);
    }
    out[rowA * B + tid] = oA;
    out[rowB * B + tid] = oB;
}

extern "C" void kernel_launch(void* const* d_in, const int* in_sizes, int n_in,
                              void* d_out, int out_size, void* d_ws, size_t ws_size,
                              hipStream_t stream) {
    const int* tokens = (const int*)d_in[0];
    const int* conn   = (const int*)d_in[1];
    const int* table  = (const int*)d_in[2];
    int* outp = (int*)d_out;

    uint8_t* ws = (uint8_t*)d_ws;
    u64*      ptok = (u64*)(ws);
    uint16_t* kcp  = (uint16_t*)(ws + 65536);
    uint16_t* pcp  = (uint16_t*)(ws + 98304);
    u64*      ptabp= (u64*)(ws + 131072);

    void* args[] = { (void*)&tokens, (void*)&conn, (void*)&table,
                     (void*)&ptok, (void*)&kcp, (void*)&pcp, (void*)&ptabp, (void*)&outp };
    hipLaunchCooperativeKernel((const void*)fused_kernel, dim3(1024), dim3(256),
                               args, 0, stream);
}

// Round 7
// 23.150 us; speedup vs baseline: 4.0922x; 4.0922x over previous
//
#include <hip/hip_runtime.h>
#include <stdint.h>

#define S 2048
#define B 256
#define THRESH 4

typedef unsigned long long u64;
typedef uint32_t u32;
typedef uint8_t u8;

// ws layout:
//  [0,      65536)   ptok : S*4 u64   (64 KB)  bit-packed token rows
//  [65536,  98304)   qc   : S*8 u16   (32 KB)
//  [98304, 131072)   kc   : S*8 u16   (32 KB)
//  [131072,163840)   pc   : S*8 u16   (32 KB)
//  [163840,196608)   tab8 : 8*4096 u8 (32 KB)  one byte per table entry

// blocks 0..S-1: per-row token pack + q/k/p contribs
// blocks S..S+31: table -> u8 (1024 entries per block, 4 per thread)
__global__ void prep_kernel(const int* __restrict__ tokens,
                            const int* __restrict__ conn,
                            const int* __restrict__ table,
                            u64* __restrict__ ptok,
                            uint16_t* __restrict__ qc,
                            uint16_t* __restrict__ kc,
                            uint16_t* __restrict__ pc,
                            u8* __restrict__ tab8) {
    const int bi = blockIdx.x;
    const int tid = threadIdx.x;

    if (bi >= S) {
        const int base = (bi - S) * 1024 + tid * 4;
        const int4 v = *(const int4*)(table + base);
        uchar4 o;
        o.x = (u8)(v.x & 1); o.y = (u8)(v.y & 1);
        o.z = (u8)(v.z & 1); o.w = (u8)(v.w & 1);
        *(uchar4*)(tab8 + base) = o;
        return;
    }

    __shared__ u64 srow[4];
    const int i = bi;
    const int lane = tid & 63, wave = tid >> 6;

    const int t = tokens[i * B + tid];
    const u64 m = __ballot(t != 0);
    if (lane == 0) {
        srow[wave] = m;
        ptok[i * 4 + wave] = m;
    }
    __syncthreads();

    if (tid < 8) {
        const int h = tid;
        int q = 0, k = 0, p = 0;
        #pragma unroll
        for (int n = 0; n < 12; ++n) {
            const int c = conn[h * 12 + n];
            if (c < B) {
                q |= (int)((srow[c >> 6] >> (c & 63)) & 1) << n;
            } else if (c < 2 * B) {
                const int cc = c - B;
                k |= (int)((srow[cc >> 6] >> (cc & 63)) & 1) << n;
            } else {
                p |= ((i >> (c - 2 * B)) & 1) << n;
            }
        }
        qc[i * 8 + h] = (uint16_t)q;
        kc[i * 8 + h] = (uint16_t)k;
        pc[i * 8 + h] = (uint16_t)p;
    }
}

__device__ __forceinline__ int vote8(const u8* s_tab8, u64 a0, u64 a1) {
    const u32 lo0 = (u32)a0, hi0 = (u32)(a0 >> 32);
    const u32 lo1 = (u32)a1, hi1 = (u32)(a1 >> 32);
    int v;
    v  = s_tab8[          (lo0 & 0xFFF)];
    v += s_tab8[ 4096 + ((lo0 >> 16) & 0xFFF)];
    v += s_tab8[ 8192 +  (hi0 & 0xFFF)];
    v += s_tab8[12288 + ((hi0 >> 16) & 0xFFF)];
    v += s_tab8[16384 +  (lo1 & 0xFFF)];
    v += s_tab8[20480 + ((lo1 >> 16) & 0xFFF)];
    v += s_tab8[24576 +  (hi1 & 0xFFF)];
    v += s_tab8[28672 + ((hi1 >> 16) & 0xFFF)];
    return v;
}

__launch_bounds__(256)
__global__ void main_kernel(const u64* __restrict__ ptok,
                            const uint16_t* __restrict__ qc,
                            const uint16_t* __restrict__ kc,
                            const uint16_t* __restrict__ pc,
                            const u8* __restrict__ tab8,
                            int* __restrict__ out) {
    __shared__ u8  s_tab8[32768];               // 32 KB u8 tables
    __shared__ u64 s_part[8][256];              // 16 KB xor staging
    __shared__ u64 s_p2[8][32];
    __shared__ u64 s_fin[8];
    __shared__ u64 s_kred[4];

    const int b   = blockIdx.x;                 // 0..1023
    const int tid = threadIdx.x;
    const int lane = tid & 63, wave = tid >> 6;

    #pragma unroll
    for (int k = 0; k < 8; ++k)
        ((uint4*)s_tab8)[tid + k * 256] = ((const uint4*)tab8)[tid + k * 256];
    __syncthreads();

    // rows: pair (2046-b, b) = exactly 2048 slots; block 1023 takes {2047,1023}
    const int rowA = (b == 1023) ? 2047 : 2046 - b;
    const int rowB = (b == 1023) ? 1023 : b;
    const int nA    = rowA + 1;
    const int total = nA + rowB + 1;            // 2048 (3072 for b==1023)
    const int niter = total >> 9;

    const ulonglong2 qA = *(const ulonglong2*)(qc + rowA * 8);
    const ulonglong2 qB = *(const ulonglong2*)(qc + rowB * 8);

    u64 ax0=0, ax1=0, ax2=0, ax3=0;
    u64 bx0=0, bx1=0, bx2=0, bx3=0;
    u32 bkA = 2047u, bkB = 2047u;               // ((v+1)<<16)|(2047-j), init v=-1,j=0

    for (int it = 0; it < niter; ++it) {
        const int v0 = (it << 9) + tid;
        const int v1 = v0 + 256;

        const bool isA0 = (v0 < nA);
        const bool isA1 = (v1 < nA);
        const int j0 = isA0 ? v0 : v0 - nA;
        const int j1 = isA1 ? v1 : v1 - nA;
        const int d0 = (isA0 ? rowA : rowB) - j0;
        const int d1 = (isA1 ? rowA : rowB) - j1;

        // issue all loads up front
        const ulonglong2 kk0 = *(const ulonglong2*)(kc + j0 * 8);
        const ulonglong2 pp0 = *(const ulonglong2*)(pc + d0 * 8);
        const ulonglong2 t00 = *(const ulonglong2*)(ptok + j0 * 4);
        const ulonglong2 t01 = *(const ulonglong2*)(ptok + j0 * 4 + 2);
        const ulonglong2 kk1 = *(const ulonglong2*)(kc + j1 * 8);
        const ulonglong2 pp1 = *(const ulonglong2*)(pc + d1 * 8);
        const ulonglong2 t10 = *(const ulonglong2*)(ptok + j1 * 4);
        const ulonglong2 t11 = *(const ulonglong2*)(ptok + j1 * 4 + 2);

        // disjoint bit-fields: no carry across 16-bit lanes
        const int vt0 = vote8(s_tab8, (isA0 ? qA.x : qB.x) + kk0.x + pp0.x,
                                      (isA0 ? qA.y : qB.y) + kk0.y + pp0.y);
        const int vt1 = vote8(s_tab8, (isA1 ? qA.x : qB.x) + kk1.x + pp1.x,
                                      (isA1 ? qA.y : qB.y) + kk1.y + pp1.y);

        const u32 vk0 = ((u32)(vt0 + 1) << 16) | (u32)(2047 - j0);
        const u32 vk1 = ((u32)(vt1 + 1) << 16) | (u32)(2047 - j1);

        // isA is wave-uniform except at the nA boundary wave
        if (isA0) { if (vk0 > bkA) bkA = vk0; } else { if (vk0 > bkB) bkB = vk0; }
        if (isA1) { if (vk1 > bkA) bkA = vk1; } else { if (vk1 > bkB) bkB = vk1; }

        if (vt0 >= THRESH) {
            if (isA0) { ax0 ^= t00.x; ax1 ^= t00.y; ax2 ^= t01.x; ax3 ^= t01.y; }
            else      { bx0 ^= t00.x; bx1 ^= t00.y; bx2 ^= t01.x; bx3 ^= t01.y; }
        }
        if (vt1 >= THRESH) {
            if (isA1) { ax0 ^= t10.x; ax1 ^= t10.y; ax2 ^= t11.x; ax3 ^= t11.y; }
            else      { bx0 ^= t10.x; bx1 ^= t10.y; bx2 ^= t11.x; bx3 ^= t11.y; }
        }
    }

    // ---- reduction: keys via tiny butterfly, xors via staged LDS tree ----
    #pragma unroll
    for (int off = 32; off; off >>= 1) {
        bkA = max(bkA, (u32)__shfl_xor((int)bkA, off));
        bkB = max(bkB, (u32)__shfl_xor((int)bkB, off));
    }

    s_part[0][tid] = ax0; s_part[1][tid] = ax1; s_part[2][tid] = ax2; s_part[3][tid] = ax3;
    s_part[4][tid] = bx0; s_part[5][tid] = bx1; s_part[6][tid] = bx2; s_part[7][tid] = bx3;
    if (lane == 0) s_kred[wave] = ((u64)bkA << 32) | bkB;
    __syncthreads();

    {   // stage 1: 8 words x 32 chunks
        const int w = tid >> 5, c = tid & 31;
        u64 x = s_part[w][c]       ^ s_part[w][c + 32]  ^ s_part[w][c + 64]  ^ s_part[w][c + 96]
              ^ s_part[w][c + 128] ^ s_part[w][c + 160] ^ s_part[w][c + 192] ^ s_part[w][c + 224];
        s_p2[w][c] = x;
    }
    __syncthreads();
    if (tid < 64) {                             // stage 2: fold 32 -> 1 per word
        const int w = tid >> 3, c = tid & 7;
        u64 x = s_p2[w][c] ^ s_p2[w][c + 8] ^ s_p2[w][c + 16] ^ s_p2[w][c + 24];
        x ^= __shfl_xor(x, 4); x ^= __shfl_xor(x, 2); x ^= __shfl_xor(x, 1);
        if (c == 0) s_fin[w] = x;
    }
    __syncthreads();

    const u32 fkA = max(max((u32)(s_kred[0] >> 32), (u32)(s_kred[1] >> 32)),
                        max((u32)(s_kred[2] >> 32), (u32)(s_kred[3] >> 32)));
    const u32 fkB = max(max((u32)s_kred[0], (u32)s_kred[1]),
                        max((u32)s_kred[2], (u32)s_kred[3]));

    const int widx = tid >> 6, bitb = tid & 63;
    int oA, oB;
    if ((fkA >> 16) > THRESH) {                 // bestv+1 > 4 <=> bestv >= THRESH
        oA = (int)((s_fin[widx] >> bitb) & 1);
    } else {
        const int bj = 2047 - (int)(fkA & 0xFFFF);
        oA = (int)((ptok[bj * 4 + widx] >> bitb) & 1);
    }
    if ((fkB >> 16) > THRESH) {
        oB = (int)((s_fin[4 + widx] >> bitb) & 1);
    } else {
        const int bj = 2047 - (int)(fkB & 0xFFFF);
        oB = (int)((ptok[bj * 4 + widx] >> bitb) & 1);
    }
    out[rowA * B + tid] = oA;
    out[rowB * B + tid] = oB;
}

extern "C" void kernel_launch(void* const* d_in, const int* in_sizes, int n_in,
                              void* d_out, int out_size, void* d_ws, size_t ws_size,
                              hipStream_t stream) {
    const int* tokens = (const int*)d_in[0];
    const int* conn   = (const int*)d_in[1];
    const int* table  = (const int*)d_in[2];
    int* outp = (int*)d_out;

    uint8_t* ws = (uint8_t*)d_ws;
    u64*      ptok = (u64*)(ws);
    uint16_t* qcp  = (uint16_t*)(ws + 65536);
    uint16_t* kcp  = (uint16_t*)(ws + 98304);
    uint16_t* pcp  = (uint16_t*)(ws + 131072);
    u8*       tab8 = (u8*)(ws + 163840);

    prep_kernel<<<S + 32, 256, 0, stream>>>(tokens, conn, table, ptok, qcp, kcp, pcp, tab8);
    main_kernel<<<S / 2, 256, 0, stream>>>(ptok, qcp, kcp, pcp, tab8, outp);
}

// Round 8
// 19.835 us; speedup vs baseline: 4.7762x; 1.1671x over previous
//
#include <hip/hip_runtime.h>
#include <stdint.h>

#define S 2048
#define B 256
#define THRESH 4

typedef unsigned long long u64;
typedef uint32_t u32;

// ws layout:
//  [0,      65536)   ptok : S*4 u64   (64 KB)  bit-packed token rows
//  [65536,  98304)   qc   : S*8 u16   (32 KB)
//  [98304, 131072)   kc   : S*8 u16   (32 KB)
//  [131072,163840)   pc   : S*8 u16   (32 KB)
//  [163840,167936)   ptab : 1024 u32  ( 4 KB)  bit-packed tables

// blocks 0..255: 8 rows each (token pack + q/k/p contribs, conn in LDS)
// blocks 256..259: table -> bitpacked u32 (256 words per block)
__global__ void prep_kernel(const int* __restrict__ tokens,
                            const int* __restrict__ conn,
                            const int* __restrict__ table,
                            u64* __restrict__ ptok,
                            uint16_t* __restrict__ qc,
                            uint16_t* __restrict__ kc,
                            uint16_t* __restrict__ pc,
                            u32* __restrict__ ptab) {
    const int bi = blockIdx.x, tid = threadIdx.x;

    if (bi >= 256) {
        // word m covers table entries [m*32, m*32+32) (head m/128)
        const int m = (bi - 256) * 256 + tid;   // 0..1023
        const int* src = table + m * 32;
        u32 v = 0;
        #pragma unroll
        for (int b = 0; b < 32; ++b) v |= (u32)(src[b] & 1) << b;
        ptab[m] = v;
        return;
    }

    __shared__ u32 s_conn[96];
    __shared__ u64 s_row[8][4];
    const int lane = tid & 63, wave = tid >> 6;

    if (tid < 96) s_conn[tid] = (u32)conn[tid];

    const int r0 = bi * 8;
    #pragma unroll
    for (int r = 0; r < 8; ++r) {
        const int t = tokens[(r0 + r) * B + tid];
        const u64 m = __ballot(t != 0);
        if (lane == 0) { s_row[r][wave] = m; ptok[(r0 + r) * 4 + wave] = m; }
    }
    __syncthreads();

    if (tid < 64) {
        const int r = tid >> 3, h = tid & 7;
        const int i = r0 + r;
        int q = 0, k = 0, p = 0;
        #pragma unroll
        for (int n = 0; n < 12; ++n) {
            const int c = (int)s_conn[h * 12 + n];
            if (c < B) {
                q |= (int)((s_row[r][c >> 6] >> (c & 63)) & 1) << n;
            } else if (c < 2 * B) {
                const int cc = c - B;
                k |= (int)((s_row[r][cc >> 6] >> (cc & 63)) & 1) << n;
            } else {
                p |= ((i >> (c - 2 * B)) & 1) << n;
            }
        }
        qc[i * 8 + h] = (uint16_t)q;
        kc[i * 8 + h] = (uint16_t)k;
        pc[i * 8 + h] = (uint16_t)p;
    }
}

// 8 table lookups for one packed address pair (a0: heads 0-3, a1: heads 4-7)
__device__ __forceinline__ int vote8(const u32* s_tab, u64 a0, u64 a1) {
    int v = 0;
    #pragma unroll
    for (int h = 0; h < 4; ++h) {
        { u32 w = (u32)(a0 >> (16 * h + 5)) & 127;
          v += (int)((s_tab[h * 128 + w] >> ((u32)(a0 >> (16 * h)) & 31)) & 1); }
        { u32 w = (u32)(a1 >> (16 * h + 5)) & 127;
          v += (int)((s_tab[(h + 4) * 128 + w] >> ((u32)(a1 >> (16 * h)) & 31)) & 1); }
    }
    return v;
}

__launch_bounds__(256)
__global__ void main_kernel(const u64* __restrict__ ptok,
                            const uint16_t* __restrict__ qc,
                            const uint16_t* __restrict__ kc,
                            const uint16_t* __restrict__ pc,
                            const u32* __restrict__ ptab,
                            int* __restrict__ out) {
    __shared__ u32 s_tab[1024];                 // 4 KB bitpacked tables
    __shared__ u64 s_part[8][256];              // 16 KB xor staging
    __shared__ u64 s_p2[8][32];
    __shared__ u64 s_fin[8];
    __shared__ u64 s_kred[4];

    const int b   = blockIdx.x;                 // 0..1023
    const int tid = threadIdx.x;
    const int lane = tid & 63, wave = tid >> 6;

    ((uint4*)s_tab)[tid] = ((const uint4*)ptab)[tid];
    __syncthreads();

    // rows: pair (2046-b, b) = exactly 2048 slots; block 1023 takes {2047,1023}
    const int rowA = (b == 1023) ? 2047 : 2046 - b;
    const int rowB = (b == 1023) ? 1023 : b;
    const int nA    = rowA + 1;
    const int total = nA + rowB + 1;            // 2048 (3072 for b==1023)
    const int niter = total >> 9;

    const ulonglong2 qA = *(const ulonglong2*)(qc + rowA * 8);
    const ulonglong2 qB = *(const ulonglong2*)(qc + rowB * 8);

    u64 ax0=0, ax1=0, ax2=0, ax3=0;
    u64 bx0=0, bx1=0, bx2=0, bx3=0;
    u32 bkA = 2047u, bkB = 2047u;               // ((v+1)<<16)|(2047-j), init v=-1,j=0

    for (int it = 0; it < niter; ++it) {
        const int v0 = (it << 9) + tid;
        const int v1 = v0 + 256;

        const bool isA0 = (v0 < nA);
        const bool isA1 = (v1 < nA);
        const int j0 = isA0 ? v0 : v0 - nA;
        const int j1 = isA1 ? v1 : v1 - nA;
        const int d0 = (isA0 ? rowA : rowB) - j0;
        const int d1 = (isA1 ? rowA : rowB) - j1;

        // issue all loads up front (L2-resident, coalesced)
        const ulonglong2 kk0 = *(const ulonglong2*)(kc + j0 * 8);
        const ulonglong2 pp0 = *(const ulonglong2*)(pc + d0 * 8);
        const ulonglong2 t00 = *(const ulonglong2*)(ptok + j0 * 4);
        const ulonglong2 t01 = *(const ulonglong2*)(ptok + j0 * 4 + 2);
        const ulonglong2 kk1 = *(const ulonglong2*)(kc + j1 * 8);
        const ulonglong2 pp1 = *(const ulonglong2*)(pc + d1 * 8);
        const ulonglong2 t10 = *(const ulonglong2*)(ptok + j1 * 4);
        const ulonglong2 t11 = *(const ulonglong2*)(ptok + j1 * 4 + 2);

        // disjoint bit-fields: no carry across 16-bit head lanes
        const int vt0 = vote8(s_tab, (isA0 ? qA.x : qB.x) + kk0.x + pp0.x,
                                     (isA0 ? qA.y : qB.y) + kk0.y + pp0.y);
        const int vt1 = vote8(s_tab, (isA1 ? qA.x : qB.x) + kk1.x + pp1.x,
                                     (isA1 ? qA.y : qB.y) + kk1.y + pp1.y);

        const u32 vk0 = ((u32)(vt0 + 1) << 16) | (u32)(2047 - j0);
        const u32 vk1 = ((u32)(vt1 + 1) << 16) | (u32)(2047 - j1);

        // isA is wave-uniform except at the nA boundary wave
        if (isA0) { if (vk0 > bkA) bkA = vk0; } else { if (vk0 > bkB) bkB = vk0; }
        if (isA1) { if (vk1 > bkA) bkA = vk1; } else { if (vk1 > bkB) bkB = vk1; }

        if (vt0 >= THRESH) {
            if (isA0) { ax0 ^= t00.x; ax1 ^= t00.y; ax2 ^= t01.x; ax3 ^= t01.y; }
            else      { bx0 ^= t00.x; bx1 ^= t00.y; bx2 ^= t01.x; bx3 ^= t01.y; }
        }
        if (vt1 >= THRESH) {
            if (isA1) { ax0 ^= t10.x; ax1 ^= t10.y; ax2 ^= t11.x; ax3 ^= t11.y; }
            else      { bx0 ^= t10.x; bx1 ^= t10.y; bx2 ^= t11.x; bx3 ^= t11.y; }
        }
    }

    // ---- reduction: keys via tiny butterfly, xors via staged LDS tree ----
    #pragma unroll
    for (int off = 32; off; off >>= 1) {
        bkA = max(bkA, (u32)__shfl_xor((int)bkA, off));
        bkB = max(bkB, (u32)__shfl_xor((int)bkB, off));
    }

    s_part[0][tid] = ax0; s_part[1][tid] = ax1; s_part[2][tid] = ax2; s_part[3][tid] = ax3;
    s_part[4][tid] = bx0; s_part[5][tid] = bx1; s_part[6][tid] = bx2; s_part[7][tid] = bx3;
    if (lane == 0) s_kred[wave] = ((u64)bkA << 32) | bkB;
    __syncthreads();

    {   // stage 1: 8 words x 32 chunks
        const int w = tid >> 5, c = tid & 31;
        u64 x = s_part[w][c]       ^ s_part[w][c + 32]  ^ s_part[w][c + 64]  ^ s_part[w][c + 96]
              ^ s_part[w][c + 128] ^ s_part[w][c + 160] ^ s_part[w][c + 192] ^ s_part[w][c + 224];
        s_p2[w][c] = x;
    }
    __syncthreads();
    if (tid < 64) {                             // stage 2: fold 32 -> 1 per word
        const int w = tid >> 3, c = tid & 7;
        u64 x = s_p2[w][c] ^ s_p2[w][c + 8] ^ s_p2[w][c + 16] ^ s_p2[w][c + 24];
        x ^= __shfl_xor(x, 4); x ^= __shfl_xor(x, 2); x ^= __shfl_xor(x, 1);
        if (c == 0) s_fin[w] = x;
    }
    __syncthreads();

    const u32 fkA = max(max((u32)(s_kred[0] >> 32), (u32)(s_kred[1] >> 32)),
                        max((u32)(s_kred[2] >> 32), (u32)(s_kred[3] >> 32)));
    const u32 fkB = max(max((u32)s_kred[0], (u32)s_kred[1]),
                        max((u32)s_kred[2], (u32)s_kred[3]));

    const int widx = tid >> 6, bitb = tid & 63;
    int oA, oB;
    if ((fkA >> 16) > THRESH) {                 // bestv+1 > 4 <=> bestv >= THRESH
        oA = (int)((s_fin[widx] >> bitb) & 1);
    } else {
        const int bj = 2047 - (int)(fkA & 0xFFFF);
        oA = (int)((ptok[bj * 4 + widx] >> bitb) & 1);
    }
    if ((fkB >> 16) > THRESH) {
        oB = (int)((s_fin[4 + widx] >> bitb) & 1);
    } else {
        const int bj = 2047 - (int)(fkB & 0xFFFF);
        oB = (int)((ptok[bj * 4 + widx] >> bitb) & 1);
    }
    out[rowA * B + tid] = oA;
    out[rowB * B + tid] = oB;
}

extern "C" void kernel_launch(void* const* d_in, const int* in_sizes, int n_in,
                              void* d_out, int out_size, void* d_ws, size_t ws_size,
                              hipStream_t stream) {
    const int* tokens = (const int*)d_in[0];
    const int* conn   = (const int*)d_in[1];
    const int* table  = (const int*)d_in[2];
    int* outp = (int*)d_out;

    uint8_t* ws = (uint8_t*)d_ws;
    u64*      ptok = (u64*)(ws);
    uint16_t* qcp  = (uint16_t*)(ws + 65536);
    uint16_t* kcp  = (uint16_t*)(ws + 98304);
    uint16_t* pcp  = (uint16_t*)(ws + 131072);
    u32*      ptab = (u32*)(ws + 163840);

    prep_kernel<<<260, 256, 0, stream>>>(tokens, conn, table, ptok, qcp, kcp, pcp, ptab);
    main_kernel<<<S / 2, 256, 0, stream>>>(ptok, qcp, kcp, pcp, ptab, outp);
}